// Round 1
// baseline (965.107 us; speedup 1.0000x reference)
//
#include <hip/hip_runtime.h>

// Problem constants (from reference)
#define NB    16          // batch
#define NCO   16          // output channels
#define NCI   8           // input channels
#define DIM   64          // input spatial
#define PDIM  31          // pooled spatial (62/2)
#define SPATIAL (PDIM*PDIM)        // 961 pooled positions per (b,co,pd) plane
#define NTILE 4                    // ceil(961/256)
#define PARTS_PER_B (NCO*PDIM*NTILE)  // 1984 partials per batch
#define NPOOL 29791.0f             // 31^3

__device__ __forceinline__ float wave_reduce_sum(float v) {
#pragma unroll
    for (int off = 32; off > 0; off >>= 1)
        v += __shfl_down(v, off, 64);
    return v;
}

// One thread = one pooled output (b, co, pd, ph, pw).
// Computes 2x2x2 conv outputs (register-blocked over a 4x4x4 input cube per ci),
// applies (+conv_bias)/2, max-pools, block-reduces to one partial sum.
template<int ATOMIC>
__global__ __launch_bounds__(256)
void conv_pool_kernel(const float* __restrict__ x,
                      const float* __restrict__ w,
                      const float* __restrict__ cb,
                      float* __restrict__ part)
{
    __shared__ float w_s[NCI * 27];
    __shared__ float red[4];

    const int tid  = threadIdx.x;
    const int pd   = blockIdx.x >> 2;   // 0..30
    const int tile = blockIdx.x & 3;    // 0..3
    const int co   = blockIdx.y;
    const int b    = blockIdx.z;

    if (tid < NCI * 27) w_s[tid] = w[co * (NCI * 27) + tid];
    __syncthreads();

    const int s     = tile * 256 + tid;
    const bool valid = (s < SPATIAL);
    const int ss = valid ? s : 0;
    const int ph = ss / PDIM;
    const int pw = ss - ph * PDIM;
    const int d0 = pd * 2, h0 = ph * 2, w0 = pw * 2;

    float acc[8];
#pragma unroll
    for (int i = 0; i < 8; ++i) acc[i] = 0.f;

    const float* xb = x + (size_t)b * NCI * DIM * DIM * DIM;

#pragma unroll 1
    for (int ci = 0; ci < NCI; ++ci) {
        // Load the 4x4x4 input cube feeding this thread's 2x2x2 conv outputs.
        float xin[4][4][4];
        const float* xc = xb + (size_t)ci * DIM * DIM * DIM;
#pragma unroll
        for (int dd = 0; dd < 4; ++dd) {
#pragma unroll
            for (int hh = 0; hh < 4; ++hh) {
                const float* row = xc + ((d0 + dd) * DIM + (h0 + hh)) * DIM + w0;
                float2 a = *reinterpret_cast<const float2*>(row);      // w0 even -> 8B aligned
                float2 c = *reinterpret_cast<const float2*>(row + 2);
                xin[dd][hh][0] = a.x; xin[dd][hh][1] = a.y;
                xin[dd][hh][2] = c.x; xin[dd][hh][3] = c.y;
            }
        }
        const float* wc = &w_s[ci * 27];
#pragma unroll
        for (int kd = 0; kd < 3; ++kd)
#pragma unroll
        for (int kh = 0; kh < 3; ++kh)
#pragma unroll
        for (int kw = 0; kw < 3; ++kw) {
            const float wt = wc[(kd * 3 + kh) * 3 + kw];
#pragma unroll
            for (int od = 0; od < 2; ++od)
#pragma unroll
            for (int oh = 0; oh < 2; ++oh)
#pragma unroll
            for (int ow = 0; ow < 2; ++ow)
                acc[(od * 2 + oh) * 2 + ow] += wt * xin[od + kd][oh + kh][ow + kw];
        }
    }

    // maxpool over the 2x2x2 block; (+conv_bias)/2 commutes with max
    float m = acc[0];
#pragma unroll
    for (int i = 1; i < 8; ++i) m = fmaxf(m, acc[i]);
    m = (m + cb[co]) * 0.5f;
    float contrib = valid ? m : 0.f;

    // deterministic block reduction
    float v = wave_reduce_sum(contrib);
    const int wave = tid >> 6;
    if ((tid & 63) == 0) red[wave] = v;
    __syncthreads();
    if (tid == 0) {
        float t = red[0] + red[1] + red[2] + red[3];
        if (ATOMIC) atomicAdd(&part[b], t);
        else part[((b * NCO + co) * PDIM + pd) * NTILE + tile] = t;
    }
}

// Fixed-order reduction of per-block partials -> out[b]
__global__ __launch_bounds__(256)
void finalize_kernel(const float* __restrict__ part,
                     const float* __restrict__ bias,
                     float* __restrict__ out)
{
    __shared__ float red[4];
    const int b = blockIdx.x;
    const int tid = threadIdx.x;
    float sum = 0.f;
#pragma unroll
    for (int i = tid; i < PARTS_PER_B; i += 256)
        sum += part[b * PARTS_PER_B + i];
    float v = wave_reduce_sum(sum);
    const int wave = tid >> 6;
    if ((tid & 63) == 0) red[wave] = v;
    __syncthreads();
    if (tid == 0) {
        float bs = 0.f;
#pragma unroll
        for (int c = 0; c < NCO; ++c) bs += bias[c];
        out[b] = (red[0] + red[1] + red[2] + red[3]) * (1.0f / NPOOL) + bs;
    }
}

// Fallback path (only if d_ws is implausibly small): atomic accumulate
__global__ void zero_acc_kernel(float* __restrict__ part)
{
    if (threadIdx.x < NB) part[threadIdx.x] = 0.f;
}

__global__ void finalize_atomic_kernel(const float* __restrict__ part,
                                       const float* __restrict__ bias,
                                       float* __restrict__ out)
{
    const int t = threadIdx.x;
    if (t < NB) {
        float bs = 0.f;
#pragma unroll
        for (int c = 0; c < NCO; ++c) bs += bias[c];
        out[t] = part[t] * (1.0f / NPOOL) + bs;
    }
}

extern "C" void kernel_launch(void* const* d_in, const int* in_sizes, int n_in,
                              void* d_out, int out_size, void* d_ws, size_t ws_size,
                              hipStream_t stream) {
    const float* x    = (const float*)d_in[0];
    const float* w    = (const float*)d_in[1];
    const float* cb   = (const float*)d_in[2];
    const float* bias = (const float*)d_in[3];
    float* out  = (float*)d_out;
    float* part = (float*)d_ws;

    const size_t needed = (size_t)NB * PARTS_PER_B * sizeof(float);
    dim3 grid(PDIM * NTILE, NCO, NB);   // 124 x 16 x 16 = 31744 blocks

    if (ws_size >= needed) {
        conv_pool_kernel<0><<<grid, 256, 0, stream>>>(x, w, cb, part);
        finalize_kernel<<<NB, 256, 0, stream>>>(part, bias, out);
    } else {
        zero_acc_kernel<<<1, 64, 0, stream>>>(part);
        conv_pool_kernel<1><<<grid, 256, 0, stream>>>(x, w, cb, part);
        finalize_atomic_kernel<<<1, 64, 0, stream>>>(part, bias, out);
    }
}

// Round 2
// 75.229 us; speedup vs baseline: 12.8289x; 12.8289x over previous
//
#include <hip/hip_runtime.h>
#include <hip/hip_bf16.h>

// ---------------- problem constants ----------------
#define NB    16
#define NCO   16
#define NCI   8
#define DIM   64
#define PDIM  31            // pooled spatial
#define NPOOL 29791.0f      // 31^3
#define NOFF  28            // 27 taps + 1 zero pad
#define KGRP  7             // 28/4 k-groups of K=32 (4 taps x 8 ci)

// fast path geometry
#define PHG_N   8           // ceil(31/4) pooled-ph groups
#define BLK_PER_B (PDIM * PHG_N)   // 248 partials per batch
// LDS tile: 4 d-planes x 10 h-rows x 64 w, chunks of 8 bf16 (16B)
#define TILE_CHUNKS (4*10*64)      // 2560
#define LDS_CHUNKS  2576           // + halo-overrun pad (max read chunk 2561)

typedef __attribute__((ext_vector_type(8))) short short8;
typedef __attribute__((ext_vector_type(8))) unsigned short ushort8;
typedef __attribute__((ext_vector_type(4))) float f32x4;

__device__ __forceinline__ unsigned short f2bf(float f) {
    __hip_bfloat16 h = __float2bfloat16(f);
    return *reinterpret_cast<unsigned short*>(&h);
}

__device__ __forceinline__ float wave_reduce_sum(float v) {
#pragma unroll
    for (int off = 32; off > 0; off >>= 1)
        v += __shfl_down(v, off, 64);
    return v;
}

// ---------------- pass 1: x (B,Ci,D,D,D) fp32 -> xT[b][d][h][w][ci] bf16 ----------------
__global__ __launch_bounds__(256)
void transpose_kernel(const float* __restrict__ x, ushort8* __restrict__ xT)
{
    const int d = blockIdx.x;
    const int b = blockIdx.y;
    const int tid = threadIdx.x;
#pragma unroll 1
    for (int it = 0; it < 16; ++it) {
        const int idx = it * 256 + tid;
        const int h = idx >> 6;
        const int w = idx & 63;
        ushort8 o;
#pragma unroll
        for (int ci = 0; ci < NCI; ++ci) {
            const float v = x[((((size_t)b * NCI + ci) * DIM + d) * DIM + h) * DIM + w];
            o[ci] = f2bf(v);
        }
        xT[(((size_t)b * DIM + d) * DIM + h) * DIM + w] = o;
    }
}

// ---------------- pass 2: weights -> wT[co][off][ci] bf16, halved; off 27 = zeros ----------------
__global__ __launch_bounds__(512)
void wprep_kernel(const float* __restrict__ w, ushort8* __restrict__ wT)
{
    const int t = threadIdx.x;
    if (t >= NCO * NOFF) return;
    const int co  = t / NOFF;
    const int off = t % NOFF;
    ushort8 o;
#pragma unroll
    for (int ci = 0; ci < NCI; ++ci) {
        float v = (off < 27) ? w[(co * NCI + ci) * 27 + off] * 0.5f : 0.0f;
        o[ci] = f2bf(v);
    }
    wT[t] = o;
}

// ---------------- pass 3: MFMA conv + pool + partial sum ----------------
// block = (phg, pd, b). Computes output od in {2pd,2pd+1}, oh in [8*phg, 8*phg+8), all ow,
// pools 2x2x2, sums over co and pooled positions -> one partial float.
__global__ __launch_bounds__(256)
void conv_mfma_kernel(const ushort8* __restrict__ xT,
                      const ushort8* __restrict__ wT,
                      float* __restrict__ part)
{
    __shared__ __align__(16) short lds_s[LDS_CHUNKS * 8];
    __shared__ float red[4];

    const int tid  = threadIdx.x;
    const int wave = tid >> 6;
    const int lane = tid & 63;
    const int nlane = lane & 15;   // spatial col within m-tile
    const int o     = lane >> 4;   // tap-sub index within k-group

    const int phg = blockIdx.x;    // 0..7
    const int pd  = blockIdx.y;    // 0..30
    const int b   = blockIdx.z;    // 0..15
    const int oh0 = phg * 8;

    // --- weight fragments (A operand): wfrag[g], lane holds W[co=nlane][off=g*4+o][ci 0..7]
    short8 wfrag[KGRP];
#pragma unroll
    for (int g = 0; g < KGRP; ++g) {
        const ushort8 t = wT[nlane * NOFF + g * 4 + o];
        wfrag[g] = *reinterpret_cast<const short8*>(&t);
    }

    // --- per-lane LDS byte deltas for this lane's tap in each k-group
    int delta[KGRP];
#pragma unroll
    for (int g = 0; g < KGRP; ++g) {
        int off = g * 4 + o;
        if (off >= 27) off = 0;     // dummy tap (zero weights)
        const int kd = off / 9;
        const int r2 = off % 9;
        const int kh = r2 / 3;
        const int kw = r2 % 3;
        delta[g] = ((kd * 10 + kh) * 64 + kw) * 16;
    }

    // --- stage input tile: d in [2pd, 2pd+4), h in [oh0, oh0+10) (clamped), w all 64
    // each wave stages 10 rows of 64 chunks (1KB) via global_load_lds width=16
#pragma unroll 1
    for (int i = 0; i < 10; ++i) {
        const int r  = wave * 10 + i;          // 0..39, uniform per wave
        const int dl = r / 10;
        int h = oh0 + (r % 10);
        h = (h > 63) ? 63 : h;                 // clamp; feeds only masked outputs
        const ushort8* src = xT + ((((size_t)b * DIM + (2 * pd + dl)) * DIM + h) * DIM) + lane;
        __builtin_amdgcn_global_load_lds(
            (const __attribute__((address_space(1))) unsigned int*)src,
            (__attribute__((address_space(3))) unsigned int*)&lds_s[(size_t)r * 64 * 8],
            16, 0, 0);
    }
    __syncthreads();

    // --- compute: wave = pooled-ph sub-index (php)
    float lsum = 0.0f;
    const int ph_global = phg * 4 + wave;
    if (ph_global < PDIM) {
        const char* ldsb = reinterpret_cast<const char*>(lds_s);
#pragma unroll 1
        for (int owt = 0; owt < 4; ++owt) {
            int base_mt[4];
#pragma unroll
            for (int mt = 0; mt < 4; ++mt) {
                const int od_l = mt >> 1;
                const int oh_l = 2 * wave + (mt & 1);
                base_mt[mt] = ((od_l * 10 + oh_l) * 64 + owt * 16 + nlane) * 16;
            }
            f32x4 acc[4];
#pragma unroll
            for (int mt = 0; mt < 4; ++mt) acc[mt] = (f32x4){0.f, 0.f, 0.f, 0.f};

#pragma unroll
            for (int g = 0; g < KGRP; ++g) {
#pragma unroll
                for (int mt = 0; mt < 4; ++mt) {
                    const short8 bfrag = *reinterpret_cast<const short8*>(
                        ldsb + base_mt[mt] + delta[g]);
                    acc[mt] = __builtin_amdgcn_mfma_f32_16x16x32_bf16(
                        wfrag[g], bfrag, acc[mt], 0, 0, 0);
                }
            }
            // pool: max over (od pair, oh pair) = the 4 m-tiles, elementwise
            f32x4 mx;
#pragma unroll
            for (int r = 0; r < 4; ++r)
                mx[r] = fmaxf(fmaxf(acc[0][r], acc[1][r]), fmaxf(acc[2][r], acc[3][r]));
            // max over ow pair: neighbor lane (n even/odd)
            float4 pooled;
            pooled.x = fmaxf(mx[0], __shfl_xor(mx[0], 1, 64));
            pooled.y = fmaxf(mx[1], __shfl_xor(mx[1], 1, 64));
            pooled.z = fmaxf(mx[2], __shfl_xor(mx[2], 1, 64));
            pooled.w = fmaxf(mx[3], __shfl_xor(mx[3], 1, 64));
            // even-n lanes own pooled pw = owt*8 + n/2; mask pw >= 31
            const int pw = owt * 8 + (nlane >> 1);
            if (((lane & 1) == 0) && (pw < PDIM))
                lsum += (pooled.x + pooled.y) + (pooled.z + pooled.w);  // sum 4 co values
        }
    }

    // --- block reduce -> one partial
    const float v = wave_reduce_sum(lsum);
    if ((lane) == 0) red[wave] = v;
    __syncthreads();
    if (tid == 0)
        part[((size_t)b * PDIM + pd) * PHG_N + phg] = (red[0] + red[1]) + (red[2] + red[3]);
}

// ---------------- pass 4: finalize ----------------
__global__ __launch_bounds__(256)
void finalize2_kernel(const float* __restrict__ part,
                      const float* __restrict__ cb,
                      const float* __restrict__ bias,
                      float* __restrict__ out)
{
    __shared__ float red[4];
    const int b = blockIdx.x;
    const int tid = threadIdx.x;
    float s = (tid < BLK_PER_B) ? part[(size_t)b * BLK_PER_B + tid] : 0.0f;
    s = wave_reduce_sum(s);
    if ((tid & 63) == 0) red[tid >> 6] = s;
    __syncthreads();
    if (tid == 0) {
        float bc = 0.0f;
#pragma unroll
        for (int c = 0; c < NCO; ++c) bc += 0.5f * cb[c] + bias[c];
        out[b] = (red[0] + red[1] + red[2] + red[3]) * (1.0f / NPOOL) + bc;
    }
}

// ================= fallback fp32 path (small ws) =================
#define SPATIAL (PDIM*PDIM)
#define NTILE 4

__global__ __launch_bounds__(256)
void conv_pool_fb_kernel(const float* __restrict__ x,
                         const float* __restrict__ w,
                         const float* __restrict__ cb,
                         float* __restrict__ part)
{
    __shared__ float w_s[NCI * 27];
    __shared__ float red[4];
    const int tid  = threadIdx.x;
    const int pd   = blockIdx.x >> 2;
    const int tile = blockIdx.x & 3;
    const int co   = blockIdx.y;
    const int b    = blockIdx.z;
    if (tid < NCI * 27) w_s[tid] = w[co * (NCI * 27) + tid];
    __syncthreads();
    const int s = tile * 256 + tid;
    const bool valid = (s < SPATIAL);
    const int ss = valid ? s : 0;
    const int ph = ss / PDIM;
    const int pw = ss - ph * PDIM;
    const int d0 = pd * 2, h0 = ph * 2, w0 = pw * 2;
    float acc[8];
#pragma unroll
    for (int i = 0; i < 8; ++i) acc[i] = 0.f;
    const float* xb = x + (size_t)b * NCI * DIM * DIM * DIM;
#pragma unroll 1
    for (int ci = 0; ci < NCI; ++ci) {
        float xin[4][4][4];
        const float* xc = xb + (size_t)ci * DIM * DIM * DIM;
#pragma unroll
        for (int dd = 0; dd < 4; ++dd)
#pragma unroll
            for (int hh = 0; hh < 4; ++hh) {
                const float* row = xc + ((d0 + dd) * DIM + (h0 + hh)) * DIM + w0;
                float2 a = *reinterpret_cast<const float2*>(row);
                float2 c = *reinterpret_cast<const float2*>(row + 2);
                xin[dd][hh][0] = a.x; xin[dd][hh][1] = a.y;
                xin[dd][hh][2] = c.x; xin[dd][hh][3] = c.y;
            }
        const float* wc = &w_s[ci * 27];
#pragma unroll
        for (int kd = 0; kd < 3; ++kd)
#pragma unroll
        for (int kh = 0; kh < 3; ++kh)
#pragma unroll
        for (int kw = 0; kw < 3; ++kw) {
            const float wt = wc[(kd * 3 + kh) * 3 + kw];
#pragma unroll
            for (int od = 0; od < 2; ++od)
#pragma unroll
            for (int oh = 0; oh < 2; ++oh)
#pragma unroll
            for (int ow = 0; ow < 2; ++ow)
                acc[(od * 2 + oh) * 2 + ow] += wt * xin[od + kd][oh + kh][ow + kw];
        }
    }
    float m = acc[0];
#pragma unroll
    for (int i = 1; i < 8; ++i) m = fmaxf(m, acc[i]);
    m = (m + cb[co]) * 0.5f;
    float contrib = valid ? m : 0.f;
    float v = wave_reduce_sum(contrib);
    if ((tid & 63) == 0) red[tid >> 6] = v;
    __syncthreads();
    if (tid == 0) atomicAdd(&part[b], red[0] + red[1] + red[2] + red[3]);
}

__global__ void zero_acc_kernel(float* __restrict__ part)
{
    if (threadIdx.x < NB) part[threadIdx.x] = 0.f;
}

__global__ void finalize_atomic_kernel(const float* __restrict__ part,
                                       const float* __restrict__ bias,
                                       const float* __restrict__ cb,
                                       float* __restrict__ out)
{
    const int t = threadIdx.x;
    if (t < NB) {
        float bs = 0.f;
#pragma unroll
        for (int c = 0; c < NCO; ++c) bs += bias[c];
        out[t] = part[t] * (1.0f / NPOOL) + bs;
    }
}

// ================= launcher =================
extern "C" void kernel_launch(void* const* d_in, const int* in_sizes, int n_in,
                              void* d_out, int out_size, void* d_ws, size_t ws_size,
                              hipStream_t stream) {
    const float* x    = (const float*)d_in[0];
    const float* w    = (const float*)d_in[1];
    const float* cb   = (const float*)d_in[2];
    const float* bias = (const float*)d_in[3];
    float* out = (float*)d_out;

    const size_t XT_CHUNKS = (size_t)NB * DIM * DIM * DIM;     // 4,194,304 (x16B = 64MB)
    const size_t WT_CHUNKS = (size_t)NCO * NOFF;               // 448
    const size_t part_off  = (XT_CHUNKS + WT_CHUNKS) * 16;     // bytes
    const size_t needed    = part_off + (size_t)NB * BLK_PER_B * sizeof(float);

    if (ws_size >= needed) {
        char* wsb = (char*)d_ws;
        ushort8* xT  = (ushort8*)wsb;
        ushort8* wT  = xT + XT_CHUNKS;
        float*   prt = (float*)(wsb + part_off);

        transpose_kernel<<<dim3(DIM, NB), 256, 0, stream>>>(x, xT);
        wprep_kernel<<<1, 512, 0, stream>>>(w, wT);
        conv_mfma_kernel<<<dim3(PHG_N, PDIM, NB), 256, 0, stream>>>(xT, wT, prt);
        finalize2_kernel<<<NB, 256, 0, stream>>>(prt, cb, bias, out);
    } else {
        float* prt = (float*)d_ws;
        zero_acc_kernel<<<1, 64, 0, stream>>>(prt);
        dim3 grid(PDIM * NTILE, NCO, NB);
        conv_pool_fb_kernel<<<grid, 256, 0, stream>>>(x, w, cb, prt);
        finalize_atomic_kernel<<<1, 64, 0, stream>>>(prt, bias, cb, out);
    }
}

// Round 3
// 42.769 us; speedup vs baseline: 22.5655x; 1.7590x over previous
//
#include <hip/hip_runtime.h>

// ---------------- problem constants ----------------
#define NB    16
#define NCO   16
#define NCI   8
#define DIM   64
#define PDIM  31            // pooled spatial
#define NPOOL 29791.0f      // 31^3
#define NOFF  28            // 27 taps + 1 zero pad
#define KGRP  7             // 28/4 k-groups of K=32 (4 taps x 8 ci)
#define WSCALE 16.0f        // weight pre-scale (power of 2, unscaled in finalize)

// fast path geometry
#define PHG_N   8                  // ceil(31/4) pooled-ph groups
#define BLK_PER_B (PDIM * PHG_N)   // 248 partials per batch
// LDS tile: 4 d-planes x 10 h-rows x 64 w, chunks of 8 fp8 (8B = 8 ci)
#define TILE_CHUNKS (4*10*64)      // 2560
#define LDS_CHUNKS  2576           // + halo-overrun pad (max read chunk 2561)

typedef __attribute__((ext_vector_type(4))) float f32x4;

__device__ __forceinline__ float wave_reduce_sum(float v) {
#pragma unroll
    for (int off = 32; off > 0; off >>= 1)
        v += __shfl_down(v, off, 64);
    return v;
}

__device__ __forceinline__ unsigned int pack4_fp8(float a, float b, float c, float d) {
    int v = __builtin_amdgcn_cvt_pk_fp8_f32(a, b, 0, false);   // bytes 0,1
    v = __builtin_amdgcn_cvt_pk_fp8_f32(c, d, v, true);        // bytes 2,3
    return (unsigned int)v;
}

// ---------------- pass 1: weights -> wT[co][off] = 8 fp8 (ci 0..7), scaled by 0.5*WSCALE ----------------
__global__ __launch_bounds__(512)
void wprep8_kernel(const float* __restrict__ w, long* __restrict__ wT)
{
    const int t = threadIdx.x;
    if (t >= NCO * NOFF) return;
    const int co  = t / NOFF;
    const int off = t % NOFF;
    float v[8];
#pragma unroll
    for (int ci = 0; ci < NCI; ++ci)
        v[ci] = (off < 27) ? w[(co * NCI + ci) * 27 + off] * (0.5f * WSCALE) : 0.0f;
    const unsigned int lo = pack4_fp8(v[0], v[1], v[2], v[3]);
    const unsigned int hi = pack4_fp8(v[4], v[5], v[6], v[7]);
    wT[t] = (long)(((unsigned long long)hi << 32) | lo);
}

// ---------------- pass 2: fused stage(fp32->fp8 LDS) + MFMA conv + pool + partial sum ----------------
// block = (phg, pd, b). Output od in {2pd,2pd+1}, oh in [8*phg, 8*phg+8), all ow.
__global__ __launch_bounds__(256, 4)
void conv_fused_kernel(const float* __restrict__ x,
                       const long* __restrict__ wT,
                       float* __restrict__ part)
{
    __shared__ __align__(16) unsigned long long lds8[LDS_CHUNKS];
    __shared__ float red[4];

    const int tid   = threadIdx.x;
    const int wave  = tid >> 6;
    const int lane  = tid & 63;
    const int nlane = lane & 15;   // spatial col within n-tile
    const int o     = lane >> 4;   // tap-sub index within k-group

    const int phg = blockIdx.x;    // 0..7
    const int pd  = blockIdx.y;    // 0..30
    const int b   = blockIdx.z;    // 0..15
    const int oh0 = phg * 8;

    // --- weight fragments (A operand): lane holds W[co=nlane][off=g*4+o][ci 0..7]
    long wfrag[KGRP];
#pragma unroll
    for (int g = 0; g < KGRP; ++g)
        wfrag[g] = wT[nlane * NOFF + g * 4 + o];

    // --- per-lane LDS byte deltas for this lane's tap in each k-group
    int delta[KGRP];
#pragma unroll
    for (int g = 0; g < KGRP; ++g) {
        int off = g * 4 + o;
        if (off >= 27) off = 0;     // dummy tap (zero weights)
        const int kd = off / 9;
        const int r2 = off % 9;
        const int kh = r2 / 3;
        const int kw = r2 % 3;
        delta[g] = ((kd * 10 + kh) * 64 + kw) * 8;
    }

    // --- stage tile: d in [2pd,2pd+4), h in [oh0,oh0+10) clamped, all 64 w, 8 ci -> fp8
    // unit = (row r = dl*10+hl, w-quad q): 8x float4 loads, pack, 2x ds_write_b128
#pragma unroll 1
    for (int u = tid; u < 640; u += 256) {
        const int r  = u >> 4;
        const int q  = u & 15;
        const int dl = r / 10;
        const int hl = r - dl * 10;
        int h = oh0 + hl;
        h = (h > 63) ? 63 : h;      // clamp; feeds only masked outputs
        const float* src = x + ((((size_t)b * NCI) * DIM + (2 * pd + dl)) * DIM + h) * DIM + q * 4;
        f32x4 v[8];
#pragma unroll
        for (int ci = 0; ci < NCI; ++ci)
            v[ci] = *reinterpret_cast<const f32x4*>(src + (size_t)ci * DIM * DIM * DIM);
        unsigned int ow[8];
#pragma unroll
        for (int j = 0; j < 4; ++j) {
            ow[2 * j]     = pack4_fp8(v[0][j], v[1][j], v[2][j], v[3][j]);
            ow[2 * j + 1] = pack4_fp8(v[4][j], v[5][j], v[6][j], v[7][j]);
        }
        uint4* dst = reinterpret_cast<uint4*>(&lds8[(size_t)r * 64 + q * 4]);
        dst[0] = make_uint4(ow[0], ow[1], ow[2], ow[3]);
        dst[1] = make_uint4(ow[4], ow[5], ow[6], ow[7]);
    }
    __syncthreads();

    // --- compute: wave = pooled-ph sub-index
    float lsum = 0.0f;
    const int ph_global = phg * 4 + wave;
    if (ph_global < PDIM) {
        const char* ldsb = reinterpret_cast<const char*>(lds8);
#pragma unroll 1
        for (int owt = 0; owt < 4; ++owt) {
            int base_mt[4];
#pragma unroll
            for (int mt = 0; mt < 4; ++mt) {
                const int od_l = mt >> 1;
                const int oh_l = 2 * wave + (mt & 1);
                base_mt[mt] = ((od_l * 10 + oh_l) * 64 + owt * 16 + nlane) * 8;
            }
            f32x4 acc[4];
#pragma unroll
            for (int mt = 0; mt < 4; ++mt) acc[mt] = (f32x4){0.f, 0.f, 0.f, 0.f};

#pragma unroll
            for (int g = 0; g < KGRP; ++g) {
#pragma unroll
                for (int mt = 0; mt < 4; ++mt) {
                    const long bfrag = *reinterpret_cast<const long*>(
                        ldsb + base_mt[mt] + delta[g]);
                    acc[mt] = __builtin_amdgcn_mfma_f32_16x16x32_fp8_fp8(
                        wfrag[g], bfrag, acc[mt], 0, 0, 0);
                }
            }
            // pool: max over (od pair, oh pair) = the 4 m-tiles, elementwise
            f32x4 mx;
#pragma unroll
            for (int r = 0; r < 4; ++r)
                mx[r] = fmaxf(fmaxf(acc[0][r], acc[1][r]), fmaxf(acc[2][r], acc[3][r]));
            // max over ow pair: neighbor lane
            float4 pooled;
            pooled.x = fmaxf(mx[0], __shfl_xor(mx[0], 1, 64));
            pooled.y = fmaxf(mx[1], __shfl_xor(mx[1], 1, 64));
            pooled.z = fmaxf(mx[2], __shfl_xor(mx[2], 1, 64));
            pooled.w = fmaxf(mx[3], __shfl_xor(mx[3], 1, 64));
            const int pw = owt * 8 + (nlane >> 1);
            if (((lane & 1) == 0) && (pw < PDIM))
                lsum += (pooled.x + pooled.y) + (pooled.z + pooled.w);  // 4 co values
        }
    }

    // --- block reduce -> one partial
    const float v = wave_reduce_sum(lsum);
    if (lane == 0) red[wave] = v;
    __syncthreads();
    if (tid == 0)
        part[((size_t)b * PDIM + pd) * PHG_N + phg] = (red[0] + red[1]) + (red[2] + red[3]);
}

// ---------------- pass 3: finalize ----------------
__global__ __launch_bounds__(256)
void finalize2_kernel(const float* __restrict__ part,
                      const float* __restrict__ cb,
                      const float* __restrict__ bias,
                      float* __restrict__ out)
{
    __shared__ float red[4];
    const int b = blockIdx.x;
    const int tid = threadIdx.x;
    float s = (tid < BLK_PER_B) ? part[(size_t)b * BLK_PER_B + tid] : 0.0f;
    s = wave_reduce_sum(s);
    if ((tid & 63) == 0) red[tid >> 6] = s;
    __syncthreads();
    if (tid == 0) {
        float bc = 0.0f;
#pragma unroll
        for (int c = 0; c < NCO; ++c) bc += 0.5f * cb[c] + bias[c];
        out[b] = (red[0] + red[1] + red[2] + red[3]) * (1.0f / (WSCALE * NPOOL)) + bc;
    }
}

// ================= fallback fp32 path (small ws) =================
#define SPATIAL (PDIM*PDIM)
#define NTILE 4

__global__ __launch_bounds__(256)
void conv_pool_fb_kernel(const float* __restrict__ x,
                         const float* __restrict__ w,
                         const float* __restrict__ cb,
                         float* __restrict__ part)
{
    __shared__ float w_s[NCI * 27];
    __shared__ float red[4];
    const int tid  = threadIdx.x;
    const int pd   = blockIdx.x >> 2;
    const int tile = blockIdx.x & 3;
    const int co   = blockIdx.y;
    const int b    = blockIdx.z;
    if (tid < NCI * 27) w_s[tid] = w[co * (NCI * 27) + tid];
    __syncthreads();
    const int s = tile * 256 + tid;
    const bool valid = (s < SPATIAL);
    const int ss = valid ? s : 0;
    const int ph = ss / PDIM;
    const int pw = ss - ph * PDIM;
    const int d0 = pd * 2, h0 = ph * 2, w0 = pw * 2;
    float acc[8];
#pragma unroll
    for (int i = 0; i < 8; ++i) acc[i] = 0.f;
    const float* xb = x + (size_t)b * NCI * DIM * DIM * DIM;
#pragma unroll 1
    for (int ci = 0; ci < NCI; ++ci) {
        float xin[4][4][4];
        const float* xc = xb + (size_t)ci * DIM * DIM * DIM;
#pragma unroll
        for (int dd = 0; dd < 4; ++dd)
#pragma unroll
            for (int hh = 0; hh < 4; ++hh) {
                const float* row = xc + ((d0 + dd) * DIM + (h0 + hh)) * DIM + w0;
                float2 a = *reinterpret_cast<const float2*>(row);
                float2 c = *reinterpret_cast<const float2*>(row + 2);
                xin[dd][hh][0] = a.x; xin[dd][hh][1] = a.y;
                xin[dd][hh][2] = c.x; xin[dd][hh][3] = c.y;
            }
        const float* wc = &w_s[ci * 27];
#pragma unroll
        for (int kd = 0; kd < 3; ++kd)
#pragma unroll
        for (int kh = 0; kh < 3; ++kh)
#pragma unroll
        for (int kw = 0; kw < 3; ++kw) {
            const float wt = wc[(kd * 3 + kh) * 3 + kw];
#pragma unroll
            for (int od = 0; od < 2; ++od)
#pragma unroll
            for (int oh = 0; oh < 2; ++oh)
#pragma unroll
            for (int ow2 = 0; ow2 < 2; ++ow2)
                acc[(od * 2 + oh) * 2 + ow2] += wt * xin[od + kd][oh + kh][ow2 + kw];
        }
    }
    float m = acc[0];
#pragma unroll
    for (int i = 1; i < 8; ++i) m = fmaxf(m, acc[i]);
    m = (m + cb[co]) * 0.5f;
    float contrib = valid ? m : 0.f;
    float v = wave_reduce_sum(contrib);
    if ((tid & 63) == 0) red[tid >> 6] = v;
    __syncthreads();
    if (tid == 0) atomicAdd(&part[b], red[0] + red[1] + red[2] + red[3]);
}

__global__ void zero_acc_kernel(float* __restrict__ part)
{
    if (threadIdx.x < NB) part[threadIdx.x] = 0.f;
}

__global__ void finalize_atomic_kernel(const float* __restrict__ part,
                                       const float* __restrict__ bias,
                                       float* __restrict__ out)
{
    const int t = threadIdx.x;
    if (t < NB) {
        float bs = 0.f;
#pragma unroll
        for (int c = 0; c < NCO; ++c) bs += bias[c];
        out[t] = part[t] * (1.0f / NPOOL) + bs;
    }
}

// ================= launcher =================
extern "C" void kernel_launch(void* const* d_in, const int* in_sizes, int n_in,
                              void* d_out, int out_size, void* d_ws, size_t ws_size,
                              hipStream_t stream) {
    const float* x    = (const float*)d_in[0];
    const float* w    = (const float*)d_in[1];
    const float* cb   = (const float*)d_in[2];
    const float* bias = (const float*)d_in[3];
    float* out = (float*)d_out;

    const size_t WT_BYTES  = (size_t)NCO * NOFF * 8;               // 3584
    const size_t part_off  = 4096;                                 // aligned
    const size_t needed    = part_off + (size_t)NB * BLK_PER_B * sizeof(float);

    if (ws_size >= needed) {
        char* wsb = (char*)d_ws;
        long*  wT  = (long*)wsb;
        float* prt = (float*)(wsb + part_off);

        wprep8_kernel<<<1, 512, 0, stream>>>(w, wT);
        conv_fused_kernel<<<dim3(PHG_N, PDIM, NB), 256, 0, stream>>>(x, wT, prt);
        finalize2_kernel<<<NB, 256, 0, stream>>>(prt, cb, bias, out);
        (void)WT_BYTES;
    } else {
        float* prt = (float*)d_ws;
        zero_acc_kernel<<<1, 64, 0, stream>>>(prt);
        dim3 grid(PDIM * NTILE, NCO, NB);
        conv_pool_fb_kernel<<<grid, 256, 0, stream>>>(x, w, cb, prt);
        finalize_atomic_kernel<<<1, 64, 0, stream>>>(prt, bias, out);
    }
}